// Round 3
// baseline (6313.008 us; speedup 1.0000x reference)
//
#include <hip/hip_runtime.h>
#include <stdint.h>

#define B_ 4096
#define T_ 80
#define E_ 100
#define V_ 10000
#define U_ 1024

typedef unsigned short u16;
typedef __attribute__((ext_vector_type(8))) __bf16 bf16x8;
typedef __attribute__((ext_vector_type(4))) float f32x4;

__device__ __forceinline__ float bf2f(u16 u) {
    union { unsigned int i; float f; } v; v.i = ((unsigned int)u) << 16; return v.f;
}
__device__ __forceinline__ u16 f2bf(float f) {
    union { float f; unsigned int i; } v; v.f = f;
    unsigned int x = v.i;
    return (u16)((x + 0x7fffu + ((x >> 16) & 1u)) >> 16);
}

// dst[n*Kp + k] = bf16( (k < K) ? src[k*N + n] : 0 )  — f32 in, bf16 out, transpose + K-pad
__global__ void transpose_pad(const float* __restrict__ src, u16* __restrict__ dst,
                              int K, int N, int Kp)
{
    __shared__ u16 tile[32][33];
    const int k0 = blockIdx.x * 32;
    const int n0 = blockIdx.y * 32;
    const int tx = threadIdx.x & 31;
    const int ty = threadIdx.x >> 5;  // 0..7
#pragma unroll
    for (int i = 0; i < 4; i++) {
        int k = k0 + ty + i * 8;
        tile[ty + i * 8][tx] = (k < K) ? f2bf(src[(size_t)k * N + (n0 + tx)]) : (u16)0;
    }
    __syncthreads();
#pragma unroll
    for (int i = 0; i < 4; i++) {
        int n = n0 + ty + i * 8;
        dst[(size_t)n * Kp + (k0 + tx)] = tile[tx][ty + i * 8];
    }
}

// embP[v][k] = bf16( (k < 100) ? emb[v][k] : 0 ), k in [0,128)
__global__ void embed_pad(const float* __restrict__ emb, u16* __restrict__ dst)
{
    int id = blockIdx.x * 256 + threadIdx.x;   // V_*128 total
    int v = id >> 7, k = id & 127;
    dst[id] = (k < E_) ? f2bf(emb[v * E_ + k]) : (u16)0;
}

// C[4096,1024] = tanh( A1 @ W1 + A2 @ W2 + bias ), weights pre-transposed [N][K] bf16.
// GATHER: A1 rows come from embP[idx[b*T]] (K1 = 128, zero-padded).
template<bool GATHER>
__global__ void rnn_step(const u16* __restrict__ A1, const int* __restrict__ idx,
                         int K1, const u16* __restrict__ W1T,
                         const u16* __restrict__ A2, const u16* __restrict__ W2T,
                         const float* __restrict__ bias, u16* __restrict__ C)
{
    __shared__ u16 As[128 * 32];
    __shared__ u16 Bs[128 * 32];
    const int tid  = threadIdx.x;
    const int lane = tid & 63;
    const int wave = tid >> 6;
    const int wm = wave >> 1, wn = wave & 1;
    const int m0 = blockIdx.x * 128;
    const int n0 = blockIdx.y * 128;
    const int srow = tid >> 1;       // 0..127 staging row (2 threads/row)
    const int scol = (tid & 1) * 16; // element offset 0/16; each thread covers 16 elems (2x int4)

    const f32x4 z = {0.f, 0.f, 0.f, 0.f};
    f32x4 acc[4][4];
#pragma unroll
    for (int i = 0; i < 4; i++)
#pragma unroll
        for (int j = 0; j < 4; j++) acc[i][j] = z;

    int gv = 0;
    if (GATHER) gv = idx[(size_t)(m0 + srow) * T_];

#pragma unroll 1
    for (int seg = 0; seg < 2; ++seg) {
        const u16* Asrc; const u16* Wsrc; int ldA, ldW, KB;
        if (seg == 0) { Wsrc = W1T; ldW = K1; KB = K1 >> 5; Asrc = A1; ldA = GATHER ? 128 : U_; }
        else          { Wsrc = W2T; ldW = U_; KB = U_ >> 5; Asrc = A2; ldA = U_; }
#pragma unroll 1
        for (int kb = 0; kb < KB; ++kb) {
            const int k0 = kb * 32;
            const u16* ap;
            if (GATHER && seg == 0) ap = Asrc + (size_t)gv * 128 + k0 + scol;
            else                    ap = Asrc + (size_t)(m0 + srow) * ldA + k0 + scol;
            const u16* bp = Wsrc + (size_t)(n0 + srow) * ldW + k0 + scol;
            // full tile = 128x32 u16 = 8 KB; 256 threads x 32 B = two int4 each
            *reinterpret_cast<int4*>(As + srow * 32 + scol) =
                *reinterpret_cast<const int4*>(ap);
            *reinterpret_cast<int4*>(As + srow * 32 + scol + 8) =
                *reinterpret_cast<const int4*>(ap + 8);
            *reinterpret_cast<int4*>(Bs + srow * 32 + scol) =
                *reinterpret_cast<const int4*>(bp);
            *reinterpret_cast<int4*>(Bs + srow * 32 + scol + 8) =
                *reinterpret_cast<const int4*>(bp + 8);
            __syncthreads();
            bf16x8 af[4], bfr[4];
#pragma unroll
            for (int i = 0; i < 4; i++)
                af[i] = *reinterpret_cast<const bf16x8*>(
                    As + (wm * 64 + i * 16 + (lane & 15)) * 32 + (lane >> 4) * 8);
#pragma unroll
            for (int j = 0; j < 4; j++)
                bfr[j] = *reinterpret_cast<const bf16x8*>(
                    Bs + (wn * 64 + j * 16 + (lane & 15)) * 32 + (lane >> 4) * 8);
#pragma unroll
            for (int i = 0; i < 4; i++)
#pragma unroll
                for (int j = 0; j < 4; j++)
                    acc[i][j] = __builtin_amdgcn_mfma_f32_16x16x32_bf16(af[i], bfr[j], acc[i][j], 0, 0, 0);
            __syncthreads();
        }
    }

    // epilogue: bias + tanh, bf16 store
#pragma unroll
    for (int j = 0; j < 4; j++) {
        const int col = n0 + wn * 64 + j * 16 + (lane & 15);
        const float bv = bias[col];
#pragma unroll
        for (int i = 0; i < 4; i++) {
#pragma unroll
            for (int r = 0; r < 4; r++) {
                const int row = m0 + wm * 64 + i * 16 + ((lane >> 4) << 2) + r;
                float x = acc[i][j][r] + bv;
                x = fminf(15.f, fmaxf(-15.f, x));
                float e = __expf(2.f * x);
                C[(size_t)row * U_ + col] = f2bf((e - 1.f) / (e + 1.f));
            }
        }
    }
}

// out[b] = sigmoid( dot(h1[b,:], Wfc) + bfc ), one wave per row; f32 out
__global__ void final_dense(const u16* __restrict__ h1, const float* __restrict__ Wfc,
                            const float* __restrict__ bfc, float* __restrict__ out)
{
    const int lane = threadIdx.x & 63;
    const int wave = threadIdx.x >> 6;
    const int row = blockIdx.x * 4 + wave;
    const u16* hp = h1 + (size_t)row * U_ + lane * 16;
    const float* wp = Wfc + lane * 16;
    float s = 0.f;
#pragma unroll
    for (int i = 0; i < 16; i++) s += bf2f(hp[i]) * wp[i];
#pragma unroll
    for (int off = 32; off; off >>= 1) s += __shfl_down(s, off);
    if (lane == 0) {
        float x = s + bfc[0];
        out[row] = 1.f / (1.f + __expf(-x));
    }
}

extern "C" void kernel_launch(void* const* d_in, const int* in_sizes, int n_in,
                              void* d_out, int out_size, void* d_ws, size_t ws_size,
                              hipStream_t stream)
{
    const int*   inputs = (const int*)d_in[0];
    const float* emb    = (const float*)d_in[1];
    const float* Wx0    = (const float*)d_in[2];
    const float* Wh0    = (const float*)d_in[3];
    const float* b0     = (const float*)d_in[4];
    const float* Wx1    = (const float*)d_in[5];
    const float* Wh1    = (const float*)d_in[6];
    const float* b1     = (const float*)d_in[7];
    const float* Wfc    = (const float*)d_in[8];
    const float* bfc    = (const float*)d_in[9];

    char* ws = (char*)d_ws;
    const size_t MB = 1 << 20;
    u16* bufX = (u16*)(ws + 0 * MB);   // 8 MB each: h-state rotation (bf16 4096x1024)
    u16* bufY = (u16*)(ws + 8 * MB);
    u16* bufZ = (u16*)(ws + 16 * MB);
    u16* embP = (u16*)(ws + 24 * MB);  // 10000*128*2 = 2.56 MB bf16
    u16* Wx0T = (u16*)(ws + 27 * MB);  // [1024][128]  256 KB bf16
    u16* Wh0T = (u16*)(ws + 28 * MB);  // [1024][1024] 2 MB bf16
    u16* Wx1T = (u16*)(ws + 30 * MB);  // 2 MB
    u16* Wh1T = (u16*)(ws + 32 * MB);  // 2 MB  (total 34 MB)

    hipMemsetAsync(bufX, 0, 8 * MB, stream);
    hipMemsetAsync(bufY, 0, 8 * MB, stream);

    embed_pad<<<V_ * 128 / 256, 256, 0, stream>>>(emb, embP);
    transpose_pad<<<dim3(128 / 32, U_ / 32), 256, 0, stream>>>(Wx0, Wx0T, E_, U_, 128);
    transpose_pad<<<dim3(U_ / 32, U_ / 32), 256, 0, stream>>>(Wh0, Wh0T, U_, U_, U_);
    transpose_pad<<<dim3(U_ / 32, U_ / 32), 256, 0, stream>>>(Wx1, Wx1T, U_, U_, U_);
    transpose_pad<<<dim3(U_ / 32, U_ / 32), 256, 0, stream>>>(Wh1, Wh1T, U_, U_, U_);

    u16* h0 = bufX; u16* h1 = bufY; u16* sp = bufZ;
    dim3 grid(B_ / 128, U_ / 128);   // 32 x 8 = 256 blocks
    for (int t = 0; t < T_; ++t) {
        rnn_step<true ><<<grid, 256, 0, stream>>>(embP, inputs + t, 128, Wx0T, h0, Wh0T, b0, sp);
        rnn_step<false><<<grid, 256, 0, stream>>>(sp, nullptr, U_, Wx1T, h1, Wh1T, b1, h0);
        u16* nh0 = sp; u16* nh1 = h0; u16* nsp = h1;
        h0 = nh0; h1 = nh1; sp = nsp;
    }
    final_dense<<<B_ / 4, 256, 0, stream>>>(h1, Wfc, bfc, (float*)d_out);
}

// Round 4
// 4829.538 us; speedup vs baseline: 1.3072x; 1.3072x over previous
//
#include <hip/hip_runtime.h>
#include <stdint.h>

#define B_ 4096
#define T_ 80
#define E_ 100
#define V_ 10000
#define U_ 1024

typedef unsigned short u16;
typedef __attribute__((ext_vector_type(8))) __bf16 bf16x8;
typedef __attribute__((ext_vector_type(4))) float f32x4;

__device__ __forceinline__ float bf2f(u16 u) {
    union { unsigned int i; float f; } v; v.i = ((unsigned int)u) << 16; return v.f;
}
__device__ __forceinline__ u16 f2bf(float f) {
    union { float f; unsigned int i; } v; v.f = f;
    unsigned int x = v.i;
    return (u16)((x + 0x7fffu + ((x >> 16) & 1u)) >> 16);
}

// async global->LDS, 16 B per lane; LDS dest = wave-uniform base + lane*16 (m104 semantics)
__device__ __forceinline__ void load16(const void* g, void* l) {
    __builtin_amdgcn_global_load_lds(
        (__attribute__((address_space(1))) void*)(uintptr_t)g,
        (__attribute__((address_space(3))) void*)(uint32_t)(uintptr_t)l,
        16, 0, 0);
}

// dst[n*Kp + k] = bf16( (k < K) ? src[k*N + n] : 0 )  — f32 in, bf16 out, transpose + K-pad
__global__ void transpose_pad(const float* __restrict__ src, u16* __restrict__ dst,
                              int K, int N, int Kp)
{
    __shared__ u16 tile[32][33];
    const int k0 = blockIdx.x * 32;
    const int n0 = blockIdx.y * 32;
    const int tx = threadIdx.x & 31;
    const int ty = threadIdx.x >> 5;  // 0..7
#pragma unroll
    for (int i = 0; i < 4; i++) {
        int k = k0 + ty + i * 8;
        tile[ty + i * 8][tx] = (k < K) ? f2bf(src[(size_t)k * N + (n0 + tx)]) : (u16)0;
    }
    __syncthreads();
#pragma unroll
    for (int i = 0; i < 4; i++) {
        int n = n0 + ty + i * 8;
        dst[(size_t)n * Kp + (k0 + tx)] = tile[tx][ty + i * 8];
    }
}

// embP[v][k] = bf16( (k < 100) ? emb[v][k] : 0 ), k in [0,128)
__global__ void embed_pad(const float* __restrict__ emb, u16* __restrict__ dst)
{
    int id = blockIdx.x * 256 + threadIdx.x;   // V_*128 total
    int v = id >> 7, k = id & 127;
    dst[id] = (k < E_) ? f2bf(emb[v * E_ + k]) : (u16)0;
}

// C[4096,1024] = tanh( A1 @ W1 + A2 @ W2 + bias ), weights pre-transposed [N][K] bf16.
// Tile M=64 x N=128, BK=32, 4 waves (2x2), per-wave 32x64 (2x4 frags).
// grid = (4096/64, 1024/128) = 512 blocks -> 2 blocks/CU for barrier overlap.
// Staging: global_load_lds width 16, As 4 KB (1 call/wave), Bs 8 KB (2 calls/wave).
template<bool GATHER>
__global__ void rnn_step(const u16* __restrict__ A1, const int* __restrict__ idx,
                         int K1, const u16* __restrict__ W1T,
                         const u16* __restrict__ A2, const u16* __restrict__ W2T,
                         const float* __restrict__ bias, u16* __restrict__ C)
{
    __shared__ u16 As[64 * 32];    // 4096 B
    __shared__ u16 Bs[128 * 32];   // 8192 B
    const int tid  = threadIdx.x;
    const int lane = tid & 63;
    const int wave = tid >> 6;
    const int wm = wave >> 1, wn = wave & 1;
    const int m0 = blockIdx.x * 64;
    const int n0 = blockIdx.y * 128;

    // staging: lane covers row sr, col [sc, sc+8) elems; dest = waveBase + lane*16 B
    const int sr = wave * 16 + (lane >> 2);
    const int sc = (lane & 3) * 8;
    u16* AsW  = As + wave * 512;          // 1024 B per wave-call
    u16* BsW0 = Bs + wave * 512;          // rows [wave*16 .. +16)
    u16* BsW1 = Bs + 2048 + wave * 512;   // rows [64+wave*16 .. +16)

    const f32x4 z = {0.f, 0.f, 0.f, 0.f};
    f32x4 acc[2][4];
#pragma unroll
    for (int i = 0; i < 2; i++)
#pragma unroll
        for (int j = 0; j < 4; j++) acc[i][j] = z;

    size_t gvoff = 0;
    if (GATHER) gvoff = (size_t)idx[(size_t)(m0 + sr) * T_] * 128;

#pragma unroll 1
    for (int seg = 0; seg < 2; ++seg) {
        const u16* Asrc; const u16* Wsrc; int ldA, ldW, KB;
        if (seg == 0) { Wsrc = W1T; ldW = K1; KB = K1 >> 5; Asrc = A1; ldA = U_; }
        else          { Wsrc = W2T; ldW = U_; KB = U_ >> 5; Asrc = A2; ldA = U_; }
#pragma unroll 1
        for (int kb = 0; kb < KB; ++kb) {
            const int k0 = kb * 32;
            const u16* ap = (GATHER && seg == 0)
                ? A1 + gvoff + k0 + sc
                : Asrc + (size_t)(m0 + sr) * ldA + k0 + sc;
            load16(ap, AsW);
            load16(Wsrc + (size_t)(n0 + sr) * ldW + k0 + sc, BsW0);
            load16(Wsrc + (size_t)(n0 + 64 + sr) * ldW + k0 + sc, BsW1);
            __syncthreads();   // drains vmcnt -> LDS tiles ready
            bf16x8 af[2], bfr[4];
#pragma unroll
            for (int i = 0; i < 2; i++)
                af[i] = *reinterpret_cast<const bf16x8*>(
                    As + (wm * 32 + i * 16 + (lane & 15)) * 32 + (lane >> 4) * 8);
#pragma unroll
            for (int j = 0; j < 4; j++)
                bfr[j] = *reinterpret_cast<const bf16x8*>(
                    Bs + (wn * 64 + j * 16 + (lane & 15)) * 32 + (lane >> 4) * 8);
#pragma unroll
            for (int i = 0; i < 2; i++)
#pragma unroll
                for (int j = 0; j < 4; j++)
                    acc[i][j] = __builtin_amdgcn_mfma_f32_16x16x32_bf16(af[i], bfr[j], acc[i][j], 0, 0, 0);
            __syncthreads();   // protect LDS from next iter's overwrite
        }
    }

    // epilogue: bias + tanh, bf16 store
#pragma unroll
    for (int j = 0; j < 4; j++) {
        const int col = n0 + wn * 64 + j * 16 + (lane & 15);
        const float bv = bias[col];
#pragma unroll
        for (int i = 0; i < 2; i++) {
#pragma unroll
            for (int r = 0; r < 4; r++) {
                const int row = m0 + wm * 32 + i * 16 + ((lane >> 4) << 2) + r;
                float x = acc[i][j][r] + bv;
                x = fminf(15.f, fmaxf(-15.f, x));
                float e = __expf(2.f * x);
                C[(size_t)row * U_ + col] = f2bf((e - 1.f) / (e + 1.f));
            }
        }
    }
}

// out[b] = sigmoid( dot(h1[b,:], Wfc) + bfc ), one wave per row; f32 out
__global__ void final_dense(const u16* __restrict__ h1, const float* __restrict__ Wfc,
                            const float* __restrict__ bfc, float* __restrict__ out)
{
    const int lane = threadIdx.x & 63;
    const int wave = threadIdx.x >> 6;
    const int row = blockIdx.x * 4 + wave;
    const u16* hp = h1 + (size_t)row * U_ + lane * 16;
    const float* wp = Wfc + lane * 16;
    float s = 0.f;
#pragma unroll
    for (int i = 0; i < 16; i++) s += bf2f(hp[i]) * wp[i];
#pragma unroll
    for (int off = 32; off; off >>= 1) s += __shfl_down(s, off);
    if (lane == 0) {
        float x = s + bfc[0];
        out[row] = 1.f / (1.f + __expf(-x));
    }
}

extern "C" void kernel_launch(void* const* d_in, const int* in_sizes, int n_in,
                              void* d_out, int out_size, void* d_ws, size_t ws_size,
                              hipStream_t stream)
{
    const int*   inputs = (const int*)d_in[0];
    const float* emb    = (const float*)d_in[1];
    const float* Wx0    = (const float*)d_in[2];
    const float* Wh0    = (const float*)d_in[3];
    const float* b0     = (const float*)d_in[4];
    const float* Wx1    = (const float*)d_in[5];
    const float* Wh1    = (const float*)d_in[6];
    const float* b1     = (const float*)d_in[7];
    const float* Wfc    = (const float*)d_in[8];
    const float* bfc    = (const float*)d_in[9];

    char* ws = (char*)d_ws;
    const size_t MB = 1 << 20;
    u16* bufX = (u16*)(ws + 0 * MB);   // 8 MB each: h-state rotation (bf16 4096x1024)
    u16* bufY = (u16*)(ws + 8 * MB);
    u16* bufZ = (u16*)(ws + 16 * MB);
    u16* embP = (u16*)(ws + 24 * MB);  // 10000*128*2 = 2.56 MB bf16
    u16* Wx0T = (u16*)(ws + 27 * MB);  // [1024][128]  256 KB bf16
    u16* Wh0T = (u16*)(ws + 28 * MB);  // [1024][1024] 2 MB bf16
    u16* Wx1T = (u16*)(ws + 30 * MB);  // 2 MB
    u16* Wh1T = (u16*)(ws + 32 * MB);  // 2 MB  (total 34 MB)

    hipMemsetAsync(bufX, 0, 8 * MB, stream);
    hipMemsetAsync(bufY, 0, 8 * MB, stream);

    embed_pad<<<V_ * 128 / 256, 256, 0, stream>>>(emb, embP);
    transpose_pad<<<dim3(128 / 32, U_ / 32), 256, 0, stream>>>(Wx0, Wx0T, E_, U_, 128);
    transpose_pad<<<dim3(U_ / 32, U_ / 32), 256, 0, stream>>>(Wh0, Wh0T, U_, U_, U_);
    transpose_pad<<<dim3(U_ / 32, U_ / 32), 256, 0, stream>>>(Wx1, Wx1T, U_, U_, U_);
    transpose_pad<<<dim3(U_ / 32, U_ / 32), 256, 0, stream>>>(Wh1, Wh1T, U_, U_, U_);

    u16* h0 = bufX; u16* h1 = bufY; u16* sp = bufZ;
    dim3 grid(B_ / 64, U_ / 128);   // 64 x 8 = 512 blocks -> 2 blocks/CU
    for (int t = 0; t < T_; ++t) {
        rnn_step<true ><<<grid, 256, 0, stream>>>(embP, inputs + t, 128, Wx0T, h0, Wh0T, b0, sp);
        rnn_step<false><<<grid, 256, 0, stream>>>(sp, nullptr, U_, Wx1T, h1, Wh1T, b1, h0);
        u16* nh0 = sp; u16* nh1 = h0; u16* nsp = h1;
        h0 = nh0; h1 = nh1; sp = nsp;
    }
    final_dense<<<B_ / 4, 256, 0, stream>>>(h1, Wfc, bfc, (float*)d_out);
}

// Round 5
// 4275.666 us; speedup vs baseline: 1.4765x; 1.1295x over previous
//
#include <hip/hip_runtime.h>
#include <stdint.h>

#define B_ 4096
#define T_ 80
#define E_ 100
#define V_ 10000
#define U_ 1024

typedef unsigned short u16;
typedef __attribute__((ext_vector_type(8))) __bf16 bf16x8;
typedef __attribute__((ext_vector_type(4))) float f32x4;

__device__ __forceinline__ float bf2f(u16 u) {
    union { unsigned int i; float f; } v; v.i = ((unsigned int)u) << 16; return v.f;
}
__device__ __forceinline__ u16 f2bf(float f) {
    union { float f; unsigned int i; } v; v.f = f;
    unsigned int x = v.i;
    return (u16)((x + 0x7fffu + ((x >> 16) & 1u)) >> 16);
}

// async global->LDS, 16 B per lane; LDS dest = wave-uniform base + lane*16 (m104 semantics)
__device__ __forceinline__ void load16(const void* g, void* l) {
    __builtin_amdgcn_global_load_lds(
        (__attribute__((address_space(1))) void*)(uintptr_t)g,
        (__attribute__((address_space(3))) void*)(uint32_t)(uintptr_t)l,
        16, 0, 0);
}

// dst[n*Kp + k] = bf16( (k < K) ? src[k*N + n] : 0 )  — f32 in, bf16 out, transpose + K-pad
__global__ void transpose_pad(const float* __restrict__ src, u16* __restrict__ dst,
                              int K, int N, int Kp)
{
    __shared__ u16 tile[32][33];
    const int k0 = blockIdx.x * 32;
    const int n0 = blockIdx.y * 32;
    const int tx = threadIdx.x & 31;
    const int ty = threadIdx.x >> 5;  // 0..7
#pragma unroll
    for (int i = 0; i < 4; i++) {
        int k = k0 + ty + i * 8;
        tile[ty + i * 8][tx] = (k < K) ? f2bf(src[(size_t)k * N + (n0 + tx)]) : (u16)0;
    }
    __syncthreads();
#pragma unroll
    for (int i = 0; i < 4; i++) {
        int n = n0 + ty + i * 8;
        dst[(size_t)n * Kp + (k0 + tx)] = tile[tx][ty + i * 8];
    }
}

// embP[v][k] = bf16( (k < 100) ? emb[v][k] : 0 ), k in [0,128)
__global__ void embed_pad(const float* __restrict__ emb, u16* __restrict__ dst)
{
    int id = blockIdx.x * 256 + threadIdx.x;   // V_*128 total
    int v = id >> 7, k = id & 127;
    dst[id] = (k < E_) ? f2bf(emb[v * E_ + k]) : (u16)0;
}

// C[4096,1024] = tanh( A1 @ W1 + A2 @ W2 + bias ), weights pre-transposed [N][K] bf16.
// Tile M=64 x N=128, BK=32, 4 waves (2x2), per-wave 32x64 (2x4 frags), grid 512 -> 2 blocks/CU.
// Software pipeline: double-buffered LDS; prefetch(u+1) issued AFTER the barrier so its
// vmem flight overlaps compute(u); the next iteration's barrier (compiler vmcnt(0) drain)
// is what waits for it. One barrier per K-iter. Both K-segments fused into one flat loop.
template<bool GATHER>
__global__ void rnn_step(const u16* __restrict__ A1, const int* __restrict__ idx,
                         int K1, const u16* __restrict__ W1T,
                         const u16* __restrict__ A2, const u16* __restrict__ W2T,
                         const float* __restrict__ bias, u16* __restrict__ C)
{
    __shared__ u16 As[2][64 * 32];    // 2 x 4 KB
    __shared__ u16 Bs[2][128 * 32];   // 2 x 8 KB
    const int tid  = threadIdx.x;
    const int lane = tid & 63;
    const int wave = tid >> 6;
    const int wm = wave >> 1, wn = wave & 1;
    const int m0 = blockIdx.x * 64;
    const int n0 = blockIdx.y * 128;

    // staging: lane covers row sr, elems [sc, sc+8); dest = waveBase + lane*16 B
    const int sr = wave * 16 + (lane >> 2);
    const int sc = (lane & 3) * 8;
    const int KB1 = K1 >> 5;
    const int TOT = KB1 + (U_ >> 5);

    size_t gvoff = 0;
    if (GATHER) gvoff = (size_t)idx[(size_t)(m0 + sr) * T_] * 128;

    const f32x4 z = {0.f, 0.f, 0.f, 0.f};
    f32x4 acc[2][4];
#pragma unroll
    for (int i = 0; i < 2; i++)
#pragma unroll
        for (int j = 0; j < 4; j++) acc[i][j] = z;

    auto stage = [&](int u, int p) {
        const u16* ap; const u16* bp0; const u16* bp1;
        if (u < KB1) {
            const int k0 = u * 32;
            ap  = GATHER ? (A1 + gvoff + k0 + sc)
                         : (A1 + (size_t)(m0 + sr) * U_ + k0 + sc);
            bp0 = W1T + (size_t)(n0 + sr) * K1 + k0 + sc;
            bp1 = W1T + (size_t)(n0 + 64 + sr) * K1 + k0 + sc;
        } else {
            const int k0 = (u - KB1) * 32;
            ap  = A2 + (size_t)(m0 + sr) * U_ + k0 + sc;
            bp0 = W2T + (size_t)(n0 + sr) * U_ + k0 + sc;
            bp1 = W2T + (size_t)(n0 + 64 + sr) * U_ + k0 + sc;
        }
        load16(ap,  As[p] + wave * 512);
        load16(bp0, Bs[p] + wave * 512);
        load16(bp1, Bs[p] + 2048 + wave * 512);
    };

    stage(0, 0);

#pragma unroll 1
    for (int u = 0; u < TOT; ++u) {
        const int p = u & 1;
        __syncthreads();               // drains vmcnt -> buf[p] ready; syncs prev compute
        if (u + 1 < TOT) stage(u + 1, p ^ 1);   // in flight during this iter's compute
        bf16x8 af[2], bfr[4];
#pragma unroll
        for (int i = 0; i < 2; i++)
            af[i] = *reinterpret_cast<const bf16x8*>(
                As[p] + (wm * 32 + i * 16 + (lane & 15)) * 32 + (lane >> 4) * 8);
#pragma unroll
        for (int j = 0; j < 4; j++)
            bfr[j] = *reinterpret_cast<const bf16x8*>(
                Bs[p] + (wn * 64 + j * 16 + (lane & 15)) * 32 + (lane >> 4) * 8);
#pragma unroll
        for (int i = 0; i < 2; i++)
#pragma unroll
            for (int j = 0; j < 4; j++)
                acc[i][j] = __builtin_amdgcn_mfma_f32_16x16x32_bf16(af[i], bfr[j], acc[i][j], 0, 0, 0);
    }

    // epilogue: bias + tanh, bf16 store
#pragma unroll
    for (int j = 0; j < 4; j++) {
        const int col = n0 + wn * 64 + j * 16 + (lane & 15);
        const float bv = bias[col];
#pragma unroll
        for (int i = 0; i < 2; i++) {
#pragma unroll
            for (int r = 0; r < 4; r++) {
                const int row = m0 + wm * 32 + i * 16 + ((lane >> 4) << 2) + r;
                float x = acc[i][j][r] + bv;
                x = fminf(15.f, fmaxf(-15.f, x));
                float e = __expf(2.f * x);
                C[(size_t)row * U_ + col] = f2bf((e - 1.f) / (e + 1.f));
            }
        }
    }
}

// out[b] = sigmoid( dot(h1[b,:], Wfc) + bfc ), one wave per row; f32 out
__global__ void final_dense(const u16* __restrict__ h1, const float* __restrict__ Wfc,
                            const float* __restrict__ bfc, float* __restrict__ out)
{
    const int lane = threadIdx.x & 63;
    const int wave = threadIdx.x >> 6;
    const int row = blockIdx.x * 4 + wave;
    const u16* hp = h1 + (size_t)row * U_ + lane * 16;
    const float* wp = Wfc + lane * 16;
    float s = 0.f;
#pragma unroll
    for (int i = 0; i < 16; i++) s += bf2f(hp[i]) * wp[i];
#pragma unroll
    for (int off = 32; off; off >>= 1) s += __shfl_down(s, off);
    if (lane == 0) {
        float x = s + bfc[0];
        out[row] = 1.f / (1.f + __expf(-x));
    }
}

extern "C" void kernel_launch(void* const* d_in, const int* in_sizes, int n_in,
                              void* d_out, int out_size, void* d_ws, size_t ws_size,
                              hipStream_t stream)
{
    const int*   inputs = (const int*)d_in[0];
    const float* emb    = (const float*)d_in[1];
    const float* Wx0    = (const float*)d_in[2];
    const float* Wh0    = (const float*)d_in[3];
    const float* b0     = (const float*)d_in[4];
    const float* Wx1    = (const float*)d_in[5];
    const float* Wh1    = (const float*)d_in[6];
    const float* b1     = (const float*)d_in[7];
    const float* Wfc    = (const float*)d_in[8];
    const float* bfc    = (const float*)d_in[9];

    char* ws = (char*)d_ws;
    const size_t MB = 1 << 20;
    u16* bufX = (u16*)(ws + 0 * MB);   // 8 MB each: h-state rotation (bf16 4096x1024)
    u16* bufY = (u16*)(ws + 8 * MB);
    u16* bufZ = (u16*)(ws + 16 * MB);
    u16* embP = (u16*)(ws + 24 * MB);  // 10000*128*2 = 2.56 MB bf16
    u16* Wx0T = (u16*)(ws + 27 * MB);  // [1024][128]  256 KB bf16
    u16* Wh0T = (u16*)(ws + 28 * MB);  // [1024][1024] 2 MB bf16
    u16* Wx1T = (u16*)(ws + 30 * MB);  // 2 MB
    u16* Wh1T = (u16*)(ws + 32 * MB);  // 2 MB  (total 34 MB)

    hipMemsetAsync(bufX, 0, 8 * MB, stream);
    hipMemsetAsync(bufY, 0, 8 * MB, stream);

    embed_pad<<<V_ * 128 / 256, 256, 0, stream>>>(emb, embP);
    transpose_pad<<<dim3(128 / 32, U_ / 32), 256, 0, stream>>>(Wx0, Wx0T, E_, U_, 128);
    transpose_pad<<<dim3(U_ / 32, U_ / 32), 256, 0, stream>>>(Wh0, Wh0T, U_, U_, U_);
    transpose_pad<<<dim3(U_ / 32, U_ / 32), 256, 0, stream>>>(Wx1, Wx1T, U_, U_, U_);
    transpose_pad<<<dim3(U_ / 32, U_ / 32), 256, 0, stream>>>(Wh1, Wh1T, U_, U_, U_);

    u16* h0 = bufX; u16* h1 = bufY; u16* sp = bufZ;
    dim3 grid(B_ / 64, U_ / 128);   // 64 x 8 = 512 blocks -> 2 blocks/CU
    for (int t = 0; t < T_; ++t) {
        rnn_step<true ><<<grid, 256, 0, stream>>>(embP, inputs + t, 128, Wx0T, h0, Wh0T, b0, sp);
        rnn_step<false><<<grid, 256, 0, stream>>>(sp, nullptr, U_, Wx1T, h1, Wh1T, b1, h0);
        u16* nh0 = sp; u16* nh1 = h0; u16* nsp = h1;
        h0 = nh0; h1 = nh1; sp = nsp;
    }
    final_dense<<<B_ / 4, 256, 0, stream>>>(h1, Wfc, bfc, (float*)d_out);
}

// Round 6
// 3579.386 us; speedup vs baseline: 1.7637x; 1.1945x over previous
//
#include <hip/hip_runtime.h>
#include <stdint.h>

#define B_ 4096
#define T_ 80
#define E_ 100
#define V_ 10000
#define U_ 1024

typedef unsigned short u16;
typedef __attribute__((ext_vector_type(8))) __bf16 bf16x8;
typedef __attribute__((ext_vector_type(4))) float f32x4;

__device__ __forceinline__ float bf2f(u16 u) {
    union { unsigned int i; float f; } v; v.i = ((unsigned int)u) << 16; return v.f;
}
__device__ __forceinline__ u16 f2bf(float f) {
    union { float f; unsigned int i; } v; v.f = f;
    unsigned int x = v.i;
    return (u16)((x + 0x7fffu + ((x >> 16) & 1u)) >> 16);
}

// async global->LDS, 16 B per lane; LDS dest = wave-uniform base + lane*16 (m104 semantics).
// Each lane supplies its own global address -> we can realize arbitrary 16B-granular
// permutations of the LDS layout for free (used for XOR bank swizzle below).
__device__ __forceinline__ void load16(const void* g, void* l) {
    __builtin_amdgcn_global_load_lds(
        (__attribute__((address_space(1))) void*)(uintptr_t)g,
        (__attribute__((address_space(3))) void*)(uint32_t)(uintptr_t)l,
        16, 0, 0);
}

// dst[n*Kp + k] = bf16( (k < K) ? src[k*N + n] : 0 )  — f32 in, bf16 out, transpose + K-pad
__global__ void transpose_pad(const float* __restrict__ src, u16* __restrict__ dst,
                              int K, int N, int Kp)
{
    __shared__ u16 tile[32][33];
    const int k0 = blockIdx.x * 32;
    const int n0 = blockIdx.y * 32;
    const int tx = threadIdx.x & 31;
    const int ty = threadIdx.x >> 5;  // 0..7
#pragma unroll
    for (int i = 0; i < 4; i++) {
        int k = k0 + ty + i * 8;
        tile[ty + i * 8][tx] = (k < K) ? f2bf(src[(size_t)k * N + (n0 + tx)]) : (u16)0;
    }
    __syncthreads();
#pragma unroll
    for (int i = 0; i < 4; i++) {
        int n = n0 + ty + i * 8;
        dst[(size_t)n * Kp + (k0 + tx)] = tile[tx][ty + i * 8];
    }
}

// embP[v][k] = bf16( (k < 100) ? emb[v][k] : 0 ), k in [0,128)
__global__ void embed_pad(const float* __restrict__ emb, u16* __restrict__ dst)
{
    int id = blockIdx.x * 256 + threadIdx.x;   // V_*128 total
    int v = id >> 7, k = id & 127;
    dst[id] = (k < E_) ? f2bf(emb[v * E_ + k]) : (u16)0;
}

// C[4096,1024] = tanh( A1 @ W1 + A2 @ W2 + bias ), weights pre-transposed [N][K] bf16.
// Tile M=64 x N=64, BK=64, 4 waves (2x2), per-wave 32x32 (2x2 frags x 2 k-steps).
// grid = (64,16) = 1024 blocks -> 4 blocks/CU (TLP hides the per-block ~900-cyc
// prefetch-drain latency floor). Double-buffered LDS, prefetch distance 1.
// LDS tiles XOR-swizzled at 16B granularity: LDS[r][c] = G[r][c ^ (r&7)] so BK=64
// (128 B = 32-bank rows) fragment ds_read_b128 is 2-way max instead of 16-way.
template<bool GATHER>
__global__ void __launch_bounds__(256, 4)
rnn_step(const u16* __restrict__ A1, const int* __restrict__ idx,
         int K1, const u16* __restrict__ W1T,
         const u16* __restrict__ A2, const u16* __restrict__ W2T,
         const float* __restrict__ bias, u16* __restrict__ C)
{
    __shared__ u16 As[2][64 * 64];   // 2 x 8 KB
    __shared__ u16 Bs[2][64 * 64];   // 2 x 8 KB
    const int tid  = threadIdx.x;
    const int lane = tid & 63;
    const int wave = tid >> 6;
    const int wm = wave >> 1, wn = wave & 1;
    const int m0 = blockIdx.x * 64;
    const int n0 = blockIdx.y * 64;

    // staging: call c covers rows wave*16 + c*8 + (lane>>3), swizzled col chunk
    const int r8  = lane >> 3;                  // 0..7
    const int scw = ((lane & 7) ^ r8) * 8;      // swizzled source col (elems)
    const int KB1 = K1 >> 6;
    const int TOT = KB1 + (U_ >> 6);

    int gv0 = 0, gv1 = 0;
    if (GATHER) {
        gv0 = idx[(size_t)(m0 + wave * 16 + r8) * T_];
        gv1 = idx[(size_t)(m0 + wave * 16 + 8 + r8) * T_];
    }

    const f32x4 z = {0.f, 0.f, 0.f, 0.f};
    f32x4 acc[2][2];
#pragma unroll
    for (int i = 0; i < 2; i++)
#pragma unroll
        for (int j = 0; j < 2; j++) acc[i][j] = z;

    // loop-invariant fragment read offsets (u16 elems), inverse-swizzled
    const int l15 = lane & 15, l4 = lane >> 4, l7 = lane & 7;
    int offA[2][2], offB[2][2];   // [kk][frag]
#pragma unroll
    for (int kk = 0; kk < 2; kk++)
#pragma unroll
        for (int f = 0; f < 2; f++) {
            const int cs = (((kk * 4 + l4) ^ l7) * 8);
            offA[kk][f] = (wm * 32 + f * 16 + l15) * 64 + cs;
            offB[kk][f] = (wn * 32 + f * 16 + l15) * 64 + cs;
        }

    auto stage = [&](int u, int p) {
        u16* Ad = As[p] + wave * 1024;   // rows [wave*16, wave*16+16)
        u16* Bd = Bs[p] + wave * 1024;
        if (u < KB1) {
            const int k0 = u * 64;
#pragma unroll
            for (int c = 0; c < 2; c++) {
                const int row = wave * 16 + c * 8 + r8;
                const u16* ap = GATHER
                    ? A1 + (size_t)(c ? gv1 : gv0) * 128 + k0 + scw
                    : A1 + (size_t)(m0 + row) * U_ + k0 + scw;
                load16(ap, Ad + c * 512);
                load16(W1T + (size_t)(n0 + row) * K1 + k0 + scw, Bd + c * 512);
            }
        } else {
            const int k0 = (u - KB1) * 64;
#pragma unroll
            for (int c = 0; c < 2; c++) {
                const int row = wave * 16 + c * 8 + r8;
                load16(A2 + (size_t)(m0 + row) * U_ + k0 + scw, Ad + c * 512);
                load16(W2T + (size_t)(n0 + row) * U_ + k0 + scw, Bd + c * 512);
            }
        }
    };

    stage(0, 0);

#pragma unroll 1
    for (int u = 0; u < TOT; ++u) {
        const int p = u & 1;
        __syncthreads();               // vmcnt(0) drain -> buf[p] ready
        if (u + 1 < TOT) stage(u + 1, p ^ 1);
        bf16x8 a[2][2], b[2][2];
#pragma unroll
        for (int kk = 0; kk < 2; kk++)
#pragma unroll
            for (int f = 0; f < 2; f++) {
                a[kk][f] = *reinterpret_cast<const bf16x8*>(As[p] + offA[kk][f]);
                b[kk][f] = *reinterpret_cast<const bf16x8*>(Bs[p] + offB[kk][f]);
            }
#pragma unroll
        for (int kk = 0; kk < 2; kk++)
#pragma unroll
            for (int i = 0; i < 2; i++)
#pragma unroll
                for (int j = 0; j < 2; j++)
                    acc[i][j] = __builtin_amdgcn_mfma_f32_16x16x32_bf16(a[kk][i], b[kk][j], acc[i][j], 0, 0, 0);
    }

    // epilogue: bias + tanh, bf16 store (C/D map: col = lane&15, row = (lane>>4)*4 + reg)
#pragma unroll
    for (int j = 0; j < 2; j++) {
        const int col = n0 + wn * 32 + j * 16 + l15;
        const float bv = bias[col];
#pragma unroll
        for (int i = 0; i < 2; i++) {
#pragma unroll
            for (int r = 0; r < 4; r++) {
                const int row = m0 + wm * 32 + i * 16 + (l4 << 2) + r;
                float x = acc[i][j][r] + bv;
                x = fminf(15.f, fmaxf(-15.f, x));
                float e = __expf(2.f * x);
                C[(size_t)row * U_ + col] = f2bf((e - 1.f) / (e + 1.f));
            }
        }
    }
}

// out[b] = sigmoid( dot(h1[b,:], Wfc) + bfc ), one wave per row; f32 out
__global__ void final_dense(const u16* __restrict__ h1, const float* __restrict__ Wfc,
                            const float* __restrict__ bfc, float* __restrict__ out)
{
    const int lane = threadIdx.x & 63;
    const int wave = threadIdx.x >> 6;
    const int row = blockIdx.x * 4 + wave;
    const u16* hp = h1 + (size_t)row * U_ + lane * 16;
    const float* wp = Wfc + lane * 16;
    float s = 0.f;
#pragma unroll
    for (int i = 0; i < 16; i++) s += bf2f(hp[i]) * wp[i];
#pragma unroll
    for (int off = 32; off; off >>= 1) s += __shfl_down(s, off);
    if (lane == 0) {
        float x = s + bfc[0];
        out[row] = 1.f / (1.f + __expf(-x));
    }
}

extern "C" void kernel_launch(void* const* d_in, const int* in_sizes, int n_in,
                              void* d_out, int out_size, void* d_ws, size_t ws_size,
                              hipStream_t stream)
{
    const int*   inputs = (const int*)d_in[0];
    const float* emb    = (const float*)d_in[1];
    const float* Wx0    = (const float*)d_in[2];
    const float* Wh0    = (const float*)d_in[3];
    const float* b0     = (const float*)d_in[4];
    const float* Wx1    = (const float*)d_in[5];
    const float* Wh1    = (const float*)d_in[6];
    const float* b1     = (const float*)d_in[7];
    const float* Wfc    = (const float*)d_in[8];
    const float* bfc    = (const float*)d_in[9];

    char* ws = (char*)d_ws;
    const size_t MB = 1 << 20;
    u16* bufX = (u16*)(ws + 0 * MB);   // 8 MB each: h-state rotation (bf16 4096x1024)
    u16* bufY = (u16*)(ws + 8 * MB);
    u16* bufZ = (u16*)(ws + 16 * MB);
    u16* embP = (u16*)(ws + 24 * MB);  // 10000*128*2 = 2.56 MB bf16
    u16* Wx0T = (u16*)(ws + 27 * MB);  // [1024][128]  256 KB bf16
    u16* Wh0T = (u16*)(ws + 28 * MB);  // [1024][1024] 2 MB bf16
    u16* Wx1T = (u16*)(ws + 30 * MB);  // 2 MB
    u16* Wh1T = (u16*)(ws + 32 * MB);  // 2 MB  (total 34 MB)

    hipMemsetAsync(bufX, 0, 8 * MB, stream);
    hipMemsetAsync(bufY, 0, 8 * MB, stream);

    embed_pad<<<V_ * 128 / 256, 256, 0, stream>>>(emb, embP);
    transpose_pad<<<dim3(128 / 32, U_ / 32), 256, 0, stream>>>(Wx0, Wx0T, E_, U_, 128);
    transpose_pad<<<dim3(U_ / 32, U_ / 32), 256, 0, stream>>>(Wh0, Wh0T, U_, U_, U_);
    transpose_pad<<<dim3(U_ / 32, U_ / 32), 256, 0, stream>>>(Wx1, Wx1T, U_, U_, U_);
    transpose_pad<<<dim3(U_ / 32, U_ / 32), 256, 0, stream>>>(Wh1, Wh1T, U_, U_, U_);

    u16* h0 = bufX; u16* h1 = bufY; u16* sp = bufZ;
    dim3 grid(B_ / 64, U_ / 64);   // 64 x 16 = 1024 blocks -> 4 blocks/CU
    for (int t = 0; t < T_; ++t) {
        rnn_step<true ><<<grid, 256, 0, stream>>>(embP, inputs + t, 128, Wx0T, h0, Wh0T, b0, sp);
        rnn_step<false><<<grid, 256, 0, stream>>>(sp, nullptr, U_, Wx1T, h1, Wh1T, b1, h0);
        u16* nh0 = sp; u16* nh1 = h0; u16* nsp = h1;
        h0 = nh0; h1 = nh1; sp = nsp;
    }
    final_dense<<<B_ / 4, 256, 0, stream>>>(h1, Wfc, bfc, (float*)d_out);
}